// Round 9
// baseline (379.590 us; speedup 1.0000x reference)
//
#include <hip/hip_runtime.h>

// Per-node MLP 16->256->128->6->128->256->1 (tanh...sigmoid) on
// edge_attr.reshape(500000,16). x / edge_index are dead inputs.
//
// R16: split k1 (L1-L3) / k2 (L4-L5) with HALVED per-kernel LDS so each
// kernel gets 2 blocks/CU = 4 waves/SIMD (R15 proved the fused kernel's
// 45us of stall is TLP starvation at 2 waves/SIMD; the fused form pins
// 156.7KB LDS = 1 block/CU forever). k1 LDS 79,872 B / k2 76,800 B; both
// 2x <= 163,840 with slack (R7's 80,384 didn't co-schedule -- shaved via
// 16B broadcast ZERO slot + contiguous per-kernel image regions). z (6/node
// sigma, C-layout) round-trips via d_ws (8MB each way ~ 2.5us HBM).
// Bodies are the R14-proven forms; 512T/128-VGPR shape kept (allocator's
// 2-WG/CU target now matches hardware). Falsifier: Occupancy ~18% => no
// co-residency => revert to R14 fused, declare roofline.

#define N_NODES 500000

// ---- weight-image layout in g_img (bytes) ----
// k1 region [0, 79872) -- staged to k1 LDS verbatim:
#define OFF_W1 0        // 16 x 512B  (L1: K=16, standard k-order, x -2log2e)
#define OFF_W2 8192     // 64 x 1KB   (L2, permuted k, x -4log2e)
#define OFF_W3 73728    // 4  x 1KB   (L3, permuted k, x -4log2e)
#define OFF_B1 77824    // 256 f32 (S*b1)
#define OFF_B2 78848    // 128 f32 (S*(be1 - colsum We1))
#define OFF_B3 79360    // 16 f32  (S*(be2 - colsum We2), 6 valid)
#define OFF_ZERO 79424  // 16B zeros (L1 K-pad A rows, broadcast slot)
#define K1_LDS 79872    // 4992 chunks; x2 = 159744 <= 163840 -> 2 blocks/CU
// k2 region [79872, 156672) -- staged to k2 LDS at (off - 79872):
#define K2_BASE 79872
#define OFF_W4 79872    // 8  x 1KB   (L4: z C-layout feed, x -4log2e)
#define OFF_W5 88064    // 64 x 1KB   (L5, permuted k, x -4log2e)
#define OFF_WO 153600   // 256 f32 (2*Wo)
#define OFF_B4 154624   // 128 f32 (S*(bd1 - colsum Wd1))
#define OFF_B5 155136   // 256 f32 (S*(bd2 - colsum Wd2))
#define OFF_EXTRA 156160 // 16B: [0] = bo - Sum Wo
#define IMG_END 156176
#define K2_LDS 76800    // 4800 chunks; x2 = 153600 <= 163840 -> 2 blocks/CU
#define IMG_ALLOC 156672 // = K2_BASE + K2_LDS (both regions stage cleanly)
// k2 smem-relative offsets:
#define SM_W4   0
#define SM_W5   8192
#define SM_WO   73728
#define SM_B4   74752
#define SM_B5   75264
#define SM_EXTRA 76288

#define SCONST (-2.8853900817779268f)   // -2*log2(e)

typedef _Float16 half8  __attribute__((ext_vector_type(8)));
typedef __fp16   pk16x2 __attribute__((ext_vector_type(2)));
typedef float    f32x4  __attribute__((ext_vector_type(4)));
typedef int      int4v  __attribute__((ext_vector_type(4)));

__device__ __align__(16) char g_img[IMG_ALLOC];

static __device__ __forceinline__ unsigned pack_f16_rne(float a, float b) {
  _Float16 ha = (_Float16)a, hb = (_Float16)b;
  unsigned short ua = __builtin_bit_cast(unsigned short, ha);
  unsigned short ub = __builtin_bit_cast(unsigned short, hb);
  return (unsigned)ua | ((unsigned)ub << 16);
}
static __device__ __forceinline__ int pkrtz(float a, float b) {
  pk16x2 h = __builtin_amdgcn_cvt_pkrtz(a, b);
  return __builtin_bit_cast(int, h);
}
// s = 1/(1+2^y); with y = -2*log2e*(Wx+b) this is sigma(2*(Wx+b)).
static __device__ __forceinline__ float sig2(float y) {
  float e = __builtin_amdgcn_exp2f(y);
  return __builtin_amdgcn_rcpf(1.0f + e);
}
static __device__ __forceinline__ float sigmoid_f(float x) {
  float e = __builtin_amdgcn_exp2f(x * -1.4426950408889634f);
  return __builtin_amdgcn_rcpf(1.0f + e);
}
static __device__ __forceinline__ f32x4 mfma16(half8 a, int4v b, f32x4 c) {
  return __builtin_amdgcn_mfma_f32_16x16x32_f16(a, __builtin_bit_cast(half8, b), c, 0, 0, 0);
}
static __device__ __forceinline__ half8 lda(const char* smem, int off) {
  return *(const half8*)(smem + off);
}
static __device__ __forceinline__ f32x4 ldf4(const char* smem, int off) {
  return *(const f32x4*)(smem + off);
}
#define FENCE() __builtin_amdgcn_sched_barrier(0)

struct PK2 { int lo, hi; };
static __device__ __forceinline__ PK2 tp(f32x4 a) {
  PK2 p;
  p.lo = pkrtz(sig2(a.x), sig2(a.y));
  p.hi = pkrtz(sig2(a.z), sig2(a.w));
  return p;
}

// ---------------- prep: pack (blocks 0..152) + bias reductions (153..155) ----------------
__global__ __launch_bounds__(256)
void gnn_prep(const float* __restrict__ W1,  const float* __restrict__ b1,
              const float* __restrict__ We1, const float* __restrict__ be1,
              const float* __restrict__ We2, const float* __restrict__ be2,
              const float* __restrict__ Wd1, const float* __restrict__ bd1,
              const float* __restrict__ Wd2, const float* __restrict__ bd2,
              const float* __restrict__ Wo,  const float* __restrict__ bo)
{
  __shared__ float sb[832];
  const int tid = threadIdx.x;
  const int bx = blockIdx.x;

  if (bx >= 153) {
    float* gB2 = (float*)(g_img + OFF_B2);
    float* gB3 = (float*)(g_img + OFF_B3);
    float* gB4 = (float*)(g_img + OFF_B4);
    float* gB5 = (float*)(g_img + OFF_B5);
    if (bx == 153) {            // B2: colsum We1 [256x128], coalesced across tid
      int col = tid & 127, part = tid >> 7;
      float s = 0.0f;
      for (int r = 0; r < 128; ++r) s += We1[(part * 128 + r) * 128 + col];
      sb[tid] = s;
      __syncthreads();
      if (tid < 128) gB2[tid] = SCONST * (be1[tid] - (sb[tid] + sb[128 + tid]));
    } else if (bx == 154) {     // B5: colsum Wd2 [128x256], coalesced across tid
      float s = 0.0f;
      for (int r = 0; r < 128; ++r) s += Wd2[r * 256 + tid];
      gB5[tid] = SCONST * (bd2[tid] - s);
    } else {                    // B3, B4, EXTRA
      for (int j = tid; j < 768; j += 256) sb[j] = We2[j];       // We2 [128x6]
      if (tid >= 192) {                                          // Wo partials
        int i = tid - 192;
        sb[768 + i] = Wo[4 * i] + Wo[4 * i + 1] + Wo[4 * i + 2] + Wo[4 * i + 3];
      }
      __syncthreads();
      if (tid < 6) {
        float s = 0.0f;
        for (int k = 0; k < 128; ++k) s += sb[k * 6 + tid];
        gB3[tid] = SCONST * (be2[tid] - s);
      } else if (tid < 16) {
        gB3[tid] = 0.0f;
      } else if (tid == 16) {
        float s = 0.0f;
        for (int i = 0; i < 64; ++i) s += sb[768 + i];
        *(float*)(g_img + OFF_EXTRA) = bo[0] - s;
      } else if (tid >= 32 && tid < 160) {                       // B4: Wd1 [6x128]
        int i = tid - 32;
        float s = 0.0f;
        for (int k = 0; k < 6; ++k) s += Wd1[k * 128 + i];
        gB4[i] = SCONST * (bd1[i] - s);
      }
    }
    return;
  }

  int off = (bx * 256 + tid) * 4;
  if (off >= IMG_END) return;
  // bias ranges owned by blocks 153-155:
  if ((off >= OFF_B2 && off < OFF_ZERO) ||
      (off >= OFF_B4 && off < OFF_EXTRA + 4)) return;
  unsigned val;
  if (off < OFF_W2) {                     // L1 (K=16): standard order, S*W1
    int rel = off;
    int mi = rel >> 9, li = (rel >> 4) & 31, j2 = (rel >> 2) & 3;
    int fout = mi * 16 + (li & 15);
    int k0 = (li >> 4) * 8 + j2 * 2;
    val = pack_f16_rne(SCONST * W1[k0 * 256 + fout], SCONST * W1[(k0 + 1) * 256 + fout]);
  } else if (off < OFF_W3) {              // L2: permuted k, 2S*We1
    int rel = off - OFF_W2;
    int blk = rel >> 10, li = (rel >> 4) & 63, j2 = (rel >> 2) & 3;
    int mi = blk >> 3, ki = blk & 7;
    int fout = mi * 16 + (li & 15);
    int k0 = ki * 32 + 4 * (li >> 4) + 16 * (j2 >> 1) + 2 * (j2 & 1);
    val = pack_f16_rne(2.0f * SCONST * We1[k0 * 128 + fout],
                       2.0f * SCONST * We1[(k0 + 1) * 128 + fout]);
  } else if (off < OFF_B1) {              // L3: permuted k, 2S*We2 (fout pad 16)
    int rel = off - OFF_W3;
    int ki = rel >> 10, li = (rel >> 4) & 63, j2 = (rel >> 2) & 3;
    int fo = li & 15;
    int k0 = ki * 32 + 4 * (li >> 4) + 16 * (j2 >> 1) + 2 * (j2 & 1);
    float a = (fo < 6) ? 2.0f * SCONST * We2[k0 * 6 + fo] : 0.0f;
    float b = (fo < 6) ? 2.0f * SCONST * We2[(k0 + 1) * 6 + fo] : 0.0f;
    val = pack_f16_rne(a, b);
  } else if (off < OFF_B2) {              // S*b1
    val = __builtin_bit_cast(unsigned, SCONST * b1[(off - OFF_B1) >> 2]);
  } else if (off < OFF_W4) {              // ZERO slot + gap
    val = 0;
  } else if (off < OFF_W5) {              // L4: z C-layout feed, 2S*Wd1
    int rel = off - OFF_W4;
    int mi = rel >> 10, li = (rel >> 4) & 63, j2 = (rel >> 2) & 3;
    int fout = mi * 16 + (li & 15);
    int qa = li >> 4;
    unsigned v = 0;
    if (j2 < 2) {
      int k0 = 4 * qa + 2 * j2;
      float a = (k0 < 6)     ? 2.0f * SCONST * Wd1[k0 * 128 + fout]       : 0.0f;
      float b = (k0 + 1 < 6) ? 2.0f * SCONST * Wd1[(k0 + 1) * 128 + fout] : 0.0f;
      v = pack_f16_rne(a, b);
    }
    val = v;
  } else if (off < OFF_WO) {              // L5: permuted k, 2S*Wd2
    int rel = off - OFF_W5;
    int blk = rel >> 10, li = (rel >> 4) & 63, j2 = (rel >> 2) & 3;
    int mi = blk >> 2, ki = blk & 3;
    int fout = mi * 16 + (li & 15);
    int k0 = ki * 32 + 4 * (li >> 4) + 16 * (j2 >> 1) + 2 * (j2 & 1);
    val = pack_f16_rne(2.0f * SCONST * Wd2[k0 * 256 + fout],
                       2.0f * SCONST * Wd2[(k0 + 1) * 256 + fout]);
  } else if (off < OFF_B4) {              // wo' = 2*Wo
    val = __builtin_bit_cast(unsigned, 2.0f * Wo[(off - OFF_WO) >> 2]);
  } else {                                // EXTRA tail
    val = 0;
  }
  *(unsigned*)(g_img + off) = val;
}

static __device__ __forceinline__ void stage_chunk(const char* src, char* dst) {
  __builtin_amdgcn_global_load_lds(
      (const __attribute__((address_space(1))) void*)src,
      (__attribute__((address_space(3))) void*)dst, 16, 0, 0);
}

// ================= k1: L1 -> L2 -> L3, z (sigma, C-layout) to d_ws =================
#define L1_PAIR(KO, OUT_G0, OUT_G1) do {                                   \
    half8 Ae = lda(smem, w1b + (2*(KO))*w1s);                              \
    half8 Ao = lda(smem, w1b + (2*(KO)+1)*w1s);                            \
    f32x4 be_ = ldf4(smem, OFF_B1 + (2*(KO))*64 + q*16);                   \
    f32x4 bo_ = ldf4(smem, OFF_B1 + (2*(KO)+1)*64 + q*16);                 \
    f32x4 ae0 = mfma16(Ae, b1g0, be_);                                     \
    f32x4 ae1 = mfma16(Ae, b1g1, be_);                                     \
    f32x4 ao0 = mfma16(Ao, b1g0, bo_);                                     \
    f32x4 ao1 = mfma16(Ao, b1g1, bo_);                                     \
    PK2 pe0 = tp(ae0), po0 = tp(ao0), pe1 = tp(ae1), po1 = tp(ao1);        \
    OUT_G0.x = pe0.lo; OUT_G0.y = pe0.hi; OUT_G0.z = po0.lo; OUT_G0.w = po0.hi; \
    OUT_G1.x = pe1.lo; OUT_G1.y = pe1.hi; OUT_G1.z = po1.lo; OUT_G1.w = po1.hi; \
    FENCE();                                                               \
  } while (0)

#define L2_MI(MI, ACC0, ACC1) do {                                                            \
    f32x4 bb = ldf4(smem, OFF_B2 + (MI)*64 + q*16);                                           \
    ACC0 = bb; ACC1 = bb;                                                                     \
    half8 A;                                                                                  \
    A = lda(smem, OFF_W2 + ((MI)*8+0)*1024 + ln*16); ACC0 = mfma16(A, c2g0_0, ACC0); ACC1 = mfma16(A, c2g1_0, ACC1); \
    A = lda(smem, OFF_W2 + ((MI)*8+1)*1024 + ln*16); ACC0 = mfma16(A, c2g0_1, ACC0); ACC1 = mfma16(A, c2g1_1, ACC1); \
    A = lda(smem, OFF_W2 + ((MI)*8+2)*1024 + ln*16); ACC0 = mfma16(A, c2g0_2, ACC0); ACC1 = mfma16(A, c2g1_2, ACC1); \
    A = lda(smem, OFF_W2 + ((MI)*8+3)*1024 + ln*16); ACC0 = mfma16(A, c2g0_3, ACC0); ACC1 = mfma16(A, c2g1_3, ACC1); \
    A = lda(smem, OFF_W2 + ((MI)*8+4)*1024 + ln*16); ACC0 = mfma16(A, c2g0_4, ACC0); ACC1 = mfma16(A, c2g1_4, ACC1); \
    A = lda(smem, OFF_W2 + ((MI)*8+5)*1024 + ln*16); ACC0 = mfma16(A, c2g0_5, ACC0); ACC1 = mfma16(A, c2g1_5, ACC1); \
    A = lda(smem, OFF_W2 + ((MI)*8+6)*1024 + ln*16); ACC0 = mfma16(A, c2g0_6, ACC0); ACC1 = mfma16(A, c2g1_6, ACC1); \
    A = lda(smem, OFF_W2 + ((MI)*8+7)*1024 + ln*16); ACC0 = mfma16(A, c2g0_7, ACC0); ACC1 = mfma16(A, c2g1_7, ACC1); \
  } while (0)

#define L2_PAIR(KO, OUT_G0, OUT_G1) do {                                   \
    f32x4 ve0, ve1, vo0, vo1;                                              \
    L2_MI(2*(KO),   ve0, ve1);                                             \
    FENCE();                                                               \
    L2_MI(2*(KO)+1, vo0, vo1);                                             \
    PK2 pe0 = tp(ve0), po0 = tp(vo0), pe1 = tp(ve1), po1 = tp(vo1);        \
    OUT_G0.x = pe0.lo; OUT_G0.y = pe0.hi; OUT_G0.z = po0.lo; OUT_G0.w = po0.hi; \
    OUT_G1.x = pe1.lo; OUT_G1.y = pe1.hi; OUT_G1.z = po1.lo; OUT_G1.w = po1.hi; \
    FENCE();                                                               \
  } while (0)

__global__ __launch_bounds__(512)
void gnn_k1(const float* __restrict__ ea, int4v* __restrict__ zbuf)
{
  __shared__ __align__(16) char smem[K1_LDS];
  const int tid = threadIdx.x;
  const int wv = tid >> 6, ln = tid & 63;

  // ---- stage k1 image region [0, K1_LDS) linearly ----
#pragma unroll 1
  for (int r = 0; r < 10; ++r) {
    int cb = (r * 8 + wv) << 6;               // 64 chunks (1KB) per wave-step
    if (cb < K1_LDS / 16) {
      stage_chunk(g_img + (size_t)cb * 16 + ln * 16,
                  smem + (size_t)cb * 16 + ln * 16);
    }
  }
  __syncthreads();

  const int q = ln >> 4, c = ln & 15;
  const bool qlo = (q < 2);
  // L1 A: lanes with k>=16 (q>=2) read the 16B zero slot (broadcast).
  const int lnl16 = (ln & 31) * 16;
  const int w1b = qlo ? (OFF_W1 + lnl16) : OFF_ZERO;
  const int w1s = qlo ? 512 : 0;

  const int NG = N_NODES / 32;                // 15625 exactly
  const int g0i = blockIdx.x * 8 + wv;
  const int gstep = gridDim.x << 3;
#pragma unroll 1
  for (int g = g0i; g < NG; g += gstep) {
    const int base = g * 32;

    // ---- L1 input: edge_attr as X^T (k>=16 lanes garbage is fine: A=0) ----
    int nl = base + (q >> 1) * 16 + c;
    const f32x4* ea4 = (const f32x4*)ea;
    size_t eb = (size_t)nl * 4 + (size_t)((q & 1) * 2);
    f32x4 vlo = ea4[eb];
    f32x4 vhi = ea4[eb + 1];
    int4v b1g0;
    b1g0.x = pkrtz(vlo.x, vlo.y); b1g0.y = pkrtz(vlo.z, vlo.w);
    b1g0.z = pkrtz(vhi.x, vhi.y); b1g0.w = pkrtz(vhi.z, vhi.w);
    int sh = (ln + 32) & 63;
    int4v b1g1;
    b1g1.x = __shfl(b1g0.x, sh, 64); b1g1.y = __shfl(b1g0.y, sh, 64);
    b1g1.z = __shfl(b1g0.z, sh, 64); b1g1.w = __shfl(b1g0.w, sh, 64);

    // ---- L1: 16 -> 256 -> L2 B-frags (in-lane) ----
    int4v c2g0_0, c2g0_1, c2g0_2, c2g0_3, c2g0_4, c2g0_5, c2g0_6, c2g0_7;
    int4v c2g1_0, c2g1_1, c2g1_2, c2g1_3, c2g1_4, c2g1_5, c2g1_6, c2g1_7;
    L1_PAIR(0, c2g0_0, c2g1_0);
    L1_PAIR(1, c2g0_1, c2g1_1);
    L1_PAIR(2, c2g0_2, c2g1_2);
    L1_PAIR(3, c2g0_3, c2g1_3);
    L1_PAIR(4, c2g0_4, c2g1_4);
    L1_PAIR(5, c2g0_5, c2g1_5);
    L1_PAIR(6, c2g0_6, c2g1_6);
    L1_PAIR(7, c2g0_7, c2g1_7);

    // ---- L2: 256 -> 128 -> L3 B-frags ----
    int4v c3g0_0, c3g0_1, c3g0_2, c3g0_3;
    int4v c3g1_0, c3g1_1, c3g1_2, c3g1_3;
    L2_PAIR(0, c3g0_0, c3g1_0);
    L2_PAIR(1, c3g0_1, c3g1_1);
    L2_PAIR(2, c3g0_2, c3g1_2);
    L2_PAIR(3, c3g0_3, c3g1_3);

    // ---- L3: 128 -> 6 ----
    f32x4 bb3 = ldf4(smem, OFF_B3 + q * 16);
    f32x4 z0 = bb3, z1 = bb3;
    half8 A;
    A = lda(smem, OFF_W3 + 0 * 1024 + ln * 16); z0 = mfma16(A, c3g0_0, z0); z1 = mfma16(A, c3g1_0, z1);
    A = lda(smem, OFF_W3 + 1 * 1024 + ln * 16); z0 = mfma16(A, c3g0_1, z0); z1 = mfma16(A, c3g1_1, z1);
    A = lda(smem, OFF_W3 + 2 * 1024 + ln * 16); z0 = mfma16(A, c3g0_2, z0); z1 = mfma16(A, c3g1_2, z1);
    A = lda(smem, OFF_W3 + 3 * 1024 + ln * 16); z0 = mfma16(A, c3g0_3, z0); z1 = mfma16(A, c3g1_3, z1);
    PK2 p3g0 = tp(z0);
    PK2 p3g1 = tp(z1);

    // ---- store z (sigma, C-layout); rows 0..7 on lanes 0..31 ----
    if (ln < 32) {
      int4v zv;
      zv.x = p3g0.lo; zv.y = p3g0.hi; zv.z = p3g1.lo; zv.w = p3g1.hi;
      zbuf[(size_t)g * 32 + ln] = zv;
    }
  }
}

// ================= k2: L4 -> L5 -> out =================
#define L4_MI(MI, ACC0, ACC1) do {                                         \
    f32x4 bb = ldf4(smem, SM_B4 + (MI)*64 + q*16);                         \
    half8 A = lda(smem, SM_W4 + (MI)*1024 + ln*16);                        \
    ACC0 = mfma16(A, b4g0, bb);                                            \
    ACC1 = mfma16(A, b4g1, bb);                                            \
  } while (0)

#define L4_PAIR(KO, OUT_G0, OUT_G1) do {                                   \
    f32x4 ve0, ve1, vo0, vo1;                                              \
    L4_MI(2*(KO),   ve0, ve1);                                             \
    L4_MI(2*(KO)+1, vo0, vo1);                                             \
    PK2 pe0 = tp(ve0), po0 = tp(vo0), pe1 = tp(ve1), po1 = tp(vo1);        \
    OUT_G0.x = pe0.lo; OUT_G0.y = pe0.hi; OUT_G0.z = po0.lo; OUT_G0.w = po0.hi; \
    OUT_G1.x = pe1.lo; OUT_G1.y = pe1.hi; OUT_G1.z = po1.lo; OUT_G1.w = po1.hi; \
  } while (0)

#define L5_MI(MI) do {                                                                        \
    f32x4 bb = ldf4(smem, SM_B5 + (MI)*64 + q*16);                                            \
    f32x4 a0 = bb, a1 = bb;                                                                   \
    half8 A;                                                                                  \
    A = lda(smem, SM_W5 + ((MI)*4+0)*1024 + ln*16); a0 = mfma16(A, c5g0_0, a0); a1 = mfma16(A, c5g1_0, a1); \
    A = lda(smem, SM_W5 + ((MI)*4+1)*1024 + ln*16); a0 = mfma16(A, c5g0_1, a0); a1 = mfma16(A, c5g1_1, a1); \
    A = lda(smem, SM_W5 + ((MI)*4+2)*1024 + ln*16); a0 = mfma16(A, c5g0_2, a0); a1 = mfma16(A, c5g1_2, a1); \
    A = lda(smem, SM_W5 + ((MI)*4+3)*1024 + ln*16); a0 = mfma16(A, c5g0_3, a0); a1 = mfma16(A, c5g1_3, a1); \
    f32x4 wo = ldf4(smem, SM_WO + (MI)*64 + q*16);                                            \
    part0 += sig2(a0.x)*wo.x + sig2(a0.y)*wo.y + sig2(a0.z)*wo.z + sig2(a0.w)*wo.w;           \
    part1 += sig2(a1.x)*wo.x + sig2(a1.y)*wo.y + sig2(a1.z)*wo.z + sig2(a1.w)*wo.w;           \
  } while (0)

__global__ __launch_bounds__(512)
void gnn_k2(const int4v* __restrict__ zbuf, float* __restrict__ out)
{
  __shared__ __align__(16) char smem[K2_LDS];
  const int tid = threadIdx.x;
  const int wv = tid >> 6, ln = tid & 63;

  // ---- stage k2 image region [K2_BASE, K2_BASE + K2_LDS) linearly ----
#pragma unroll 1
  for (int r = 0; r < 10; ++r) {
    int cb = (r * 8 + wv) << 6;
    if (cb < K2_LDS / 16) {
      stage_chunk(g_img + K2_BASE + (size_t)cb * 16 + ln * 16,
                  smem + (size_t)cb * 16 + ln * 16);
    }
  }
  __syncthreads();

  const int q = ln >> 4, c = ln & 15;
  const float bo2 = *(const float*)(smem + SM_EXTRA);   // bo - Sum Wo

  const int NG = N_NODES / 32;                // 15625 exactly
  const int g0i = blockIdx.x * 8 + wv;
  const int gstep = gridDim.x << 3;
#pragma unroll 1
  for (int g = g0i; g < NG; g += gstep) {
    const int base = g * 32;

    // ---- reload z (sigma); lanes 32+ rows have zero W4 rows anyway ----
    int4v zv = {0, 0, 0, 0};
    if (ln < 32) zv = zbuf[(size_t)g * 32 + ln];

    int4v b4g0, b4g1;
    b4g0.x = zv.x; b4g0.y = zv.y; b4g0.z = 0; b4g0.w = 0;
    b4g1.x = zv.z; b4g1.y = zv.w; b4g1.z = 0; b4g1.w = 0;

    // ---- L4: 6 -> 128 -> L5 B-frags ----
    int4v c5g0_0, c5g0_1, c5g0_2, c5g0_3;
    int4v c5g1_0, c5g1_1, c5g1_2, c5g1_3;
    L4_PAIR(0, c5g0_0, c5g1_0);
    L4_PAIR(1, c5g0_1, c5g1_1);
    L4_PAIR(2, c5g0_2, c5g1_2);
    L4_PAIR(3, c5g0_3, c5g1_3);

    // ---- L5 + output: out = sigma(Sum wo'*s5 + bo') ----
    float part0 = 0.0f, part1 = 0.0f;
    L5_MI(0);  L5_MI(1);  L5_MI(2);  L5_MI(3);
    L5_MI(4);  L5_MI(5);  L5_MI(6);  L5_MI(7);
    L5_MI(8);  L5_MI(9);  L5_MI(10); L5_MI(11);
    L5_MI(12); L5_MI(13); L5_MI(14); L5_MI(15);

    part0 += __shfl_xor(part0, 16, 64); part0 += __shfl_xor(part0, 32, 64);
    part1 += __shfl_xor(part1, 16, 64); part1 += __shfl_xor(part1, 32, 64);
    if (q < 2) {
      int node = base + q * 16 + c;
      float v = ((q == 0) ? part0 : part1) + bo2;
      out[node] = sigmoid_f(v);
    }
  }
}

extern "C" void kernel_launch(void* const* d_in, const int* in_sizes, int n_in,
                              void* d_out, int out_size, void* d_ws, size_t ws_size,
                              hipStream_t stream) {
  (void)in_sizes; (void)n_in; (void)ws_size; (void)out_size;
  const float* ea  = (const float*)d_in[2];
  const float* W1  = (const float*)d_in[3];
  const float* b1  = (const float*)d_in[4];
  const float* We1 = (const float*)d_in[5];
  const float* be1 = (const float*)d_in[6];
  const float* We2 = (const float*)d_in[7];
  const float* be2 = (const float*)d_in[8];
  const float* Wd1 = (const float*)d_in[9];
  const float* bd1 = (const float*)d_in[10];
  const float* Wd2 = (const float*)d_in[11];
  const float* bd2 = (const float*)d_in[12];
  const float* Wo  = (const float*)d_in[13];
  const float* bo  = (const float*)d_in[14];

  gnn_prep<<<dim3(156), dim3(256), 0, stream>>>(
      W1, b1, We1, be1, We2, be2, Wd1, bd1, Wd2, bd2, Wo, bo);
  gnn_k1<<<dim3(512), dim3(512), 0, stream>>>(ea, (int4v*)d_ws);
  gnn_k2<<<dim3(512), dim3(512), 0, stream>>>((const int4v*)d_ws, (float*)d_out);
}

// Round 10
// 232.896 us; speedup vs baseline: 1.6299x; 1.6299x over previous
//
#include <hip/hip_runtime.h>

// Per-node MLP 16->256->128->6->128->256->1 (tanh...sigmoid) on
// edge_attr.reshape(500000,16). x / edge_index are dead inputs.
//
// R17: R16 split (k1 L1-L3 / k2 L4-L5, both 2 blocks/CU) with k2's
// FENCEs RESTORED (R7 form). R16 validated the occupancy theory for k1
// (77.7 -> ~60us at 2 blocks/CU) but k2 spilled (FETCH 490MB/WRITE 257MB):
// the fence-free L4/L5 macros were only safe inside the fused kernel where
// L1/L2 constrained the scheduler; standalone, it software-pipelines the
// g-loop and hoists ~20 LDS loads over the sigma chains -> live set >> 128.
// Fences here are pressure control, not ordering. Everything else R16:
// k1 LDS 79,872 / k2 76,800 (both x2 <= 163,840), 16B broadcast ZERO slot,
// z (sigma, C-layout) via d_ws, 512T blocks, grid 512 = 2/CU exactly.

#define N_NODES 500000

// ---- weight-image layout in g_img (bytes) ----
// k1 region [0, 79872) -- staged to k1 LDS verbatim:
#define OFF_W1 0        // 16 x 512B  (L1: K=16, standard k-order, x -2log2e)
#define OFF_W2 8192     // 64 x 1KB   (L2, permuted k, x -4log2e)
#define OFF_W3 73728    // 4  x 1KB   (L3, permuted k, x -4log2e)
#define OFF_B1 77824    // 256 f32 (S*b1)
#define OFF_B2 78848    // 128 f32 (S*(be1 - colsum We1))
#define OFF_B3 79360    // 16 f32  (S*(be2 - colsum We2), 6 valid)
#define OFF_ZERO 79424  // 16B zeros (L1 K-pad A rows, broadcast slot)
#define K1_LDS 79872    // 4992 chunks; x2 = 159744 <= 163840 -> 2 blocks/CU
// k2 region [79872, 156672) -- staged to k2 LDS at (off - 79872):
#define K2_BASE 79872
#define OFF_W4 79872    // 8  x 1KB   (L4: z C-layout feed, x -4log2e)
#define OFF_W5 88064    // 64 x 1KB   (L5, permuted k, x -4log2e)
#define OFF_WO 153600   // 256 f32 (2*Wo)
#define OFF_B4 154624   // 128 f32 (S*(bd1 - colsum Wd1))
#define OFF_B5 155136   // 256 f32 (S*(bd2 - colsum Wd2))
#define OFF_EXTRA 156160 // 16B: [0] = bo - Sum Wo
#define IMG_END 156176
#define K2_LDS 76800    // 4800 chunks; x2 = 153600 <= 163840 -> 2 blocks/CU
#define IMG_ALLOC 156672 // = K2_BASE + K2_LDS (both regions stage cleanly)
// k2 smem-relative offsets:
#define SM_W4   0
#define SM_W5   8192
#define SM_WO   73728
#define SM_B4   74752
#define SM_B5   75264
#define SM_EXTRA 76288

#define SCONST (-2.8853900817779268f)   // -2*log2(e)

typedef _Float16 half8  __attribute__((ext_vector_type(8)));
typedef __fp16   pk16x2 __attribute__((ext_vector_type(2)));
typedef float    f32x4  __attribute__((ext_vector_type(4)));
typedef int      int4v  __attribute__((ext_vector_type(4)));

__device__ __align__(16) char g_img[IMG_ALLOC];

static __device__ __forceinline__ unsigned pack_f16_rne(float a, float b) {
  _Float16 ha = (_Float16)a, hb = (_Float16)b;
  unsigned short ua = __builtin_bit_cast(unsigned short, ha);
  unsigned short ub = __builtin_bit_cast(unsigned short, hb);
  return (unsigned)ua | ((unsigned)ub << 16);
}
static __device__ __forceinline__ int pkrtz(float a, float b) {
  pk16x2 h = __builtin_amdgcn_cvt_pkrtz(a, b);
  return __builtin_bit_cast(int, h);
}
// s = 1/(1+2^y); with y = -2*log2e*(Wx+b) this is sigma(2*(Wx+b)).
static __device__ __forceinline__ float sig2(float y) {
  float e = __builtin_amdgcn_exp2f(y);
  return __builtin_amdgcn_rcpf(1.0f + e);
}
static __device__ __forceinline__ float sigmoid_f(float x) {
  float e = __builtin_amdgcn_exp2f(x * -1.4426950408889634f);
  return __builtin_amdgcn_rcpf(1.0f + e);
}
static __device__ __forceinline__ f32x4 mfma16(half8 a, int4v b, f32x4 c) {
  return __builtin_amdgcn_mfma_f32_16x16x32_f16(a, __builtin_bit_cast(half8, b), c, 0, 0, 0);
}
static __device__ __forceinline__ half8 lda(const char* smem, int off) {
  return *(const half8*)(smem + off);
}
static __device__ __forceinline__ f32x4 ldf4(const char* smem, int off) {
  return *(const f32x4*)(smem + off);
}
#define FENCE() __builtin_amdgcn_sched_barrier(0)

struct PK2 { int lo, hi; };
static __device__ __forceinline__ PK2 tp(f32x4 a) {
  PK2 p;
  p.lo = pkrtz(sig2(a.x), sig2(a.y));
  p.hi = pkrtz(sig2(a.z), sig2(a.w));
  return p;
}

// ---------------- prep: pack (blocks 0..152) + bias reductions (153..155) ----------------
__global__ __launch_bounds__(256)
void gnn_prep(const float* __restrict__ W1,  const float* __restrict__ b1,
              const float* __restrict__ We1, const float* __restrict__ be1,
              const float* __restrict__ We2, const float* __restrict__ be2,
              const float* __restrict__ Wd1, const float* __restrict__ bd1,
              const float* __restrict__ Wd2, const float* __restrict__ bd2,
              const float* __restrict__ Wo,  const float* __restrict__ bo)
{
  __shared__ float sb[832];
  const int tid = threadIdx.x;
  const int bx = blockIdx.x;

  if (bx >= 153) {
    float* gB2 = (float*)(g_img + OFF_B2);
    float* gB3 = (float*)(g_img + OFF_B3);
    float* gB4 = (float*)(g_img + OFF_B4);
    float* gB5 = (float*)(g_img + OFF_B5);
    if (bx == 153) {            // B2: colsum We1 [256x128], coalesced across tid
      int col = tid & 127, part = tid >> 7;
      float s = 0.0f;
      for (int r = 0; r < 128; ++r) s += We1[(part * 128 + r) * 128 + col];
      sb[tid] = s;
      __syncthreads();
      if (tid < 128) gB2[tid] = SCONST * (be1[tid] - (sb[tid] + sb[128 + tid]));
    } else if (bx == 154) {     // B5: colsum Wd2 [128x256], coalesced across tid
      float s = 0.0f;
      for (int r = 0; r < 128; ++r) s += Wd2[r * 256 + tid];
      gB5[tid] = SCONST * (bd2[tid] - s);
    } else {                    // B3, B4, EXTRA
      for (int j = tid; j < 768; j += 256) sb[j] = We2[j];       // We2 [128x6]
      if (tid >= 192) {                                          // Wo partials
        int i = tid - 192;
        sb[768 + i] = Wo[4 * i] + Wo[4 * i + 1] + Wo[4 * i + 2] + Wo[4 * i + 3];
      }
      __syncthreads();
      if (tid < 6) {
        float s = 0.0f;
        for (int k = 0; k < 128; ++k) s += sb[k * 6 + tid];
        gB3[tid] = SCONST * (be2[tid] - s);
      } else if (tid < 16) {
        gB3[tid] = 0.0f;
      } else if (tid == 16) {
        float s = 0.0f;
        for (int i = 0; i < 64; ++i) s += sb[768 + i];
        *(float*)(g_img + OFF_EXTRA) = bo[0] - s;
      } else if (tid >= 32 && tid < 160) {                       // B4: Wd1 [6x128]
        int i = tid - 32;
        float s = 0.0f;
        for (int k = 0; k < 6; ++k) s += Wd1[k * 128 + i];
        gB4[i] = SCONST * (bd1[i] - s);
      }
    }
    return;
  }

  int off = (bx * 256 + tid) * 4;
  if (off >= IMG_END) return;
  // bias ranges owned by blocks 153-155:
  if ((off >= OFF_B2 && off < OFF_ZERO) ||
      (off >= OFF_B4 && off < OFF_EXTRA + 4)) return;
  unsigned val;
  if (off < OFF_W2) {                     // L1 (K=16): standard order, S*W1
    int rel = off;
    int mi = rel >> 9, li = (rel >> 4) & 31, j2 = (rel >> 2) & 3;
    int fout = mi * 16 + (li & 15);
    int k0 = (li >> 4) * 8 + j2 * 2;
    val = pack_f16_rne(SCONST * W1[k0 * 256 + fout], SCONST * W1[(k0 + 1) * 256 + fout]);
  } else if (off < OFF_W3) {              // L2: permuted k, 2S*We1
    int rel = off - OFF_W2;
    int blk = rel >> 10, li = (rel >> 4) & 63, j2 = (rel >> 2) & 3;
    int mi = blk >> 3, ki = blk & 7;
    int fout = mi * 16 + (li & 15);
    int k0 = ki * 32 + 4 * (li >> 4) + 16 * (j2 >> 1) + 2 * (j2 & 1);
    val = pack_f16_rne(2.0f * SCONST * We1[k0 * 128 + fout],
                       2.0f * SCONST * We1[(k0 + 1) * 128 + fout]);
  } else if (off < OFF_B1) {              // L3: permuted k, 2S*We2 (fout pad 16)
    int rel = off - OFF_W3;
    int ki = rel >> 10, li = (rel >> 4) & 63, j2 = (rel >> 2) & 3;
    int fo = li & 15;
    int k0 = ki * 32 + 4 * (li >> 4) + 16 * (j2 >> 1) + 2 * (j2 & 1);
    float a = (fo < 6) ? 2.0f * SCONST * We2[k0 * 6 + fo] : 0.0f;
    float b = (fo < 6) ? 2.0f * SCONST * We2[(k0 + 1) * 6 + fo] : 0.0f;
    val = pack_f16_rne(a, b);
  } else if (off < OFF_B2) {              // S*b1
    val = __builtin_bit_cast(unsigned, SCONST * b1[(off - OFF_B1) >> 2]);
  } else if (off < OFF_W4) {              // ZERO slot + gap
    val = 0;
  } else if (off < OFF_W5) {              // L4: z C-layout feed, 2S*Wd1
    int rel = off - OFF_W4;
    int mi = rel >> 10, li = (rel >> 4) & 63, j2 = (rel >> 2) & 3;
    int fout = mi * 16 + (li & 15);
    int qa = li >> 4;
    unsigned v = 0;
    if (j2 < 2) {
      int k0 = 4 * qa + 2 * j2;
      float a = (k0 < 6)     ? 2.0f * SCONST * Wd1[k0 * 128 + fout]       : 0.0f;
      float b = (k0 + 1 < 6) ? 2.0f * SCONST * Wd1[(k0 + 1) * 128 + fout] : 0.0f;
      v = pack_f16_rne(a, b);
    }
    val = v;
  } else if (off < OFF_WO) {              // L5: permuted k, 2S*Wd2
    int rel = off - OFF_W5;
    int blk = rel >> 10, li = (rel >> 4) & 63, j2 = (rel >> 2) & 3;
    int mi = blk >> 2, ki = blk & 3;
    int fout = mi * 16 + (li & 15);
    int k0 = ki * 32 + 4 * (li >> 4) + 16 * (j2 >> 1) + 2 * (j2 & 1);
    val = pack_f16_rne(2.0f * SCONST * Wd2[k0 * 256 + fout],
                       2.0f * SCONST * Wd2[(k0 + 1) * 256 + fout]);
  } else if (off < OFF_B4) {              // wo' = 2*Wo
    val = __builtin_bit_cast(unsigned, 2.0f * Wo[(off - OFF_WO) >> 2]);
  } else {                                // EXTRA tail
    val = 0;
  }
  *(unsigned*)(g_img + off) = val;
}

static __device__ __forceinline__ void stage_chunk(const char* src, char* dst) {
  __builtin_amdgcn_global_load_lds(
      (const __attribute__((address_space(1))) void*)src,
      (__attribute__((address_space(3))) void*)dst, 16, 0, 0);
}

// ================= k1: L1 -> L2 -> L3, z (sigma, C-layout) to d_ws =================
#define L1_PAIR(KO, OUT_G0, OUT_G1) do {                                   \
    half8 Ae = lda(smem, w1b + (2*(KO))*w1s);                              \
    half8 Ao = lda(smem, w1b + (2*(KO)+1)*w1s);                            \
    f32x4 be_ = ldf4(smem, OFF_B1 + (2*(KO))*64 + q*16);                   \
    f32x4 bo_ = ldf4(smem, OFF_B1 + (2*(KO)+1)*64 + q*16);                 \
    f32x4 ae0 = mfma16(Ae, b1g0, be_);                                     \
    f32x4 ae1 = mfma16(Ae, b1g1, be_);                                     \
    f32x4 ao0 = mfma16(Ao, b1g0, bo_);                                     \
    f32x4 ao1 = mfma16(Ao, b1g1, bo_);                                     \
    PK2 pe0 = tp(ae0), po0 = tp(ao0), pe1 = tp(ae1), po1 = tp(ao1);        \
    OUT_G0.x = pe0.lo; OUT_G0.y = pe0.hi; OUT_G0.z = po0.lo; OUT_G0.w = po0.hi; \
    OUT_G1.x = pe1.lo; OUT_G1.y = pe1.hi; OUT_G1.z = po1.lo; OUT_G1.w = po1.hi; \
    FENCE();                                                               \
  } while (0)

#define L2_MI(MI, ACC0, ACC1) do {                                                            \
    f32x4 bb = ldf4(smem, OFF_B2 + (MI)*64 + q*16);                                           \
    ACC0 = bb; ACC1 = bb;                                                                     \
    half8 A;                                                                                  \
    A = lda(smem, OFF_W2 + ((MI)*8+0)*1024 + ln*16); ACC0 = mfma16(A, c2g0_0, ACC0); ACC1 = mfma16(A, c2g1_0, ACC1); \
    A = lda(smem, OFF_W2 + ((MI)*8+1)*1024 + ln*16); ACC0 = mfma16(A, c2g0_1, ACC0); ACC1 = mfma16(A, c2g1_1, ACC1); \
    A = lda(smem, OFF_W2 + ((MI)*8+2)*1024 + ln*16); ACC0 = mfma16(A, c2g0_2, ACC0); ACC1 = mfma16(A, c2g1_2, ACC1); \
    A = lda(smem, OFF_W2 + ((MI)*8+3)*1024 + ln*16); ACC0 = mfma16(A, c2g0_3, ACC0); ACC1 = mfma16(A, c2g1_3, ACC1); \
    A = lda(smem, OFF_W2 + ((MI)*8+4)*1024 + ln*16); ACC0 = mfma16(A, c2g0_4, ACC0); ACC1 = mfma16(A, c2g1_4, ACC1); \
    A = lda(smem, OFF_W2 + ((MI)*8+5)*1024 + ln*16); ACC0 = mfma16(A, c2g0_5, ACC0); ACC1 = mfma16(A, c2g1_5, ACC1); \
    A = lda(smem, OFF_W2 + ((MI)*8+6)*1024 + ln*16); ACC0 = mfma16(A, c2g0_6, ACC0); ACC1 = mfma16(A, c2g1_6, ACC1); \
    A = lda(smem, OFF_W2 + ((MI)*8+7)*1024 + ln*16); ACC0 = mfma16(A, c2g0_7, ACC0); ACC1 = mfma16(A, c2g1_7, ACC1); \
  } while (0)

#define L2_PAIR(KO, OUT_G0, OUT_G1) do {                                   \
    f32x4 ve0, ve1, vo0, vo1;                                              \
    L2_MI(2*(KO),   ve0, ve1);                                             \
    FENCE();                                                               \
    L2_MI(2*(KO)+1, vo0, vo1);                                             \
    PK2 pe0 = tp(ve0), po0 = tp(vo0), pe1 = tp(ve1), po1 = tp(vo1);        \
    OUT_G0.x = pe0.lo; OUT_G0.y = pe0.hi; OUT_G0.z = po0.lo; OUT_G0.w = po0.hi; \
    OUT_G1.x = pe1.lo; OUT_G1.y = pe1.hi; OUT_G1.z = po1.lo; OUT_G1.w = po1.hi; \
    FENCE();                                                               \
  } while (0)

__global__ __launch_bounds__(512)
void gnn_k1(const float* __restrict__ ea, int4v* __restrict__ zbuf)
{
  __shared__ __align__(16) char smem[K1_LDS];
  const int tid = threadIdx.x;
  const int wv = tid >> 6, ln = tid & 63;

  // ---- stage k1 image region [0, K1_LDS) linearly ----
#pragma unroll 1
  for (int r = 0; r < 10; ++r) {
    int cb = (r * 8 + wv) << 6;               // 64 chunks (1KB) per wave-step
    if (cb < K1_LDS / 16) {
      stage_chunk(g_img + (size_t)cb * 16 + ln * 16,
                  smem + (size_t)cb * 16 + ln * 16);
    }
  }
  __syncthreads();

  const int q = ln >> 4, c = ln & 15;
  const bool qlo = (q < 2);
  // L1 A: lanes with k>=16 (q>=2) read the 16B zero slot (broadcast).
  const int lnl16 = (ln & 31) * 16;
  const int w1b = qlo ? (OFF_W1 + lnl16) : OFF_ZERO;
  const int w1s = qlo ? 512 : 0;

  const int NG = N_NODES / 32;                // 15625 exactly
  const int g0i = blockIdx.x * 8 + wv;
  const int gstep = gridDim.x << 3;
#pragma unroll 1
  for (int g = g0i; g < NG; g += gstep) {
    const int base = g * 32;

    // ---- L1 input: edge_attr as X^T (k>=16 lanes garbage is fine: A=0) ----
    int nl = base + (q >> 1) * 16 + c;
    const f32x4* ea4 = (const f32x4*)ea;
    size_t eb = (size_t)nl * 4 + (size_t)((q & 1) * 2);
    f32x4 vlo = ea4[eb];
    f32x4 vhi = ea4[eb + 1];
    int4v b1g0;
    b1g0.x = pkrtz(vlo.x, vlo.y); b1g0.y = pkrtz(vlo.z, vlo.w);
    b1g0.z = pkrtz(vhi.x, vhi.y); b1g0.w = pkrtz(vhi.z, vhi.w);
    int sh = (ln + 32) & 63;
    int4v b1g1;
    b1g1.x = __shfl(b1g0.x, sh, 64); b1g1.y = __shfl(b1g0.y, sh, 64);
    b1g1.z = __shfl(b1g0.z, sh, 64); b1g1.w = __shfl(b1g0.w, sh, 64);

    // ---- L1: 16 -> 256 -> L2 B-frags (in-lane) ----
    int4v c2g0_0, c2g0_1, c2g0_2, c2g0_3, c2g0_4, c2g0_5, c2g0_6, c2g0_7;
    int4v c2g1_0, c2g1_1, c2g1_2, c2g1_3, c2g1_4, c2g1_5, c2g1_6, c2g1_7;
    L1_PAIR(0, c2g0_0, c2g1_0);
    L1_PAIR(1, c2g0_1, c2g1_1);
    L1_PAIR(2, c2g0_2, c2g1_2);
    L1_PAIR(3, c2g0_3, c2g1_3);
    L1_PAIR(4, c2g0_4, c2g1_4);
    L1_PAIR(5, c2g0_5, c2g1_5);
    L1_PAIR(6, c2g0_6, c2g1_6);
    L1_PAIR(7, c2g0_7, c2g1_7);

    // ---- L2: 256 -> 128 -> L3 B-frags ----
    int4v c3g0_0, c3g0_1, c3g0_2, c3g0_3;
    int4v c3g1_0, c3g1_1, c3g1_2, c3g1_3;
    L2_PAIR(0, c3g0_0, c3g1_0);
    L2_PAIR(1, c3g0_1, c3g1_1);
    L2_PAIR(2, c3g0_2, c3g1_2);
    L2_PAIR(3, c3g0_3, c3g1_3);

    // ---- L3: 128 -> 6 ----
    f32x4 bb3 = ldf4(smem, OFF_B3 + q * 16);
    f32x4 z0 = bb3, z1 = bb3;
    half8 A;
    A = lda(smem, OFF_W3 + 0 * 1024 + ln * 16); z0 = mfma16(A, c3g0_0, z0); z1 = mfma16(A, c3g1_0, z1);
    A = lda(smem, OFF_W3 + 1 * 1024 + ln * 16); z0 = mfma16(A, c3g0_1, z0); z1 = mfma16(A, c3g1_1, z1);
    A = lda(smem, OFF_W3 + 2 * 1024 + ln * 16); z0 = mfma16(A, c3g0_2, z0); z1 = mfma16(A, c3g1_2, z1);
    A = lda(smem, OFF_W3 + 3 * 1024 + ln * 16); z0 = mfma16(A, c3g0_3, z0); z1 = mfma16(A, c3g1_3, z1);
    PK2 p3g0 = tp(z0);
    PK2 p3g1 = tp(z1);

    // ---- store z (sigma, C-layout); rows 0..7 on lanes 0..31 ----
    if (ln < 32) {
      int4v zv;
      zv.x = p3g0.lo; zv.y = p3g0.hi; zv.z = p3g1.lo; zv.w = p3g1.hi;
      zbuf[(size_t)g * 32 + ln] = zv;
    }
  }
}

// ================= k2: L4 -> L5 -> out (R7 fenced forms) =================
#define L4_MI(MI, ACC0, ACC1) do {                                         \
    f32x4 bb = ldf4(smem, SM_B4 + (MI)*64 + q*16);                         \
    half8 A = lda(smem, SM_W4 + (MI)*1024 + ln*16);                        \
    ACC0 = mfma16(A, b4g0, bb);                                            \
    ACC1 = mfma16(A, b4g1, bb);                                            \
  } while (0)

#define L4_PAIR(KO, OUT_G0, OUT_G1) do {                                   \
    f32x4 ve0, ve1, vo0, vo1;                                              \
    L4_MI(2*(KO),   ve0, ve1);                                             \
    L4_MI(2*(KO)+1, vo0, vo1);                                             \
    PK2 pe0 = tp(ve0), po0 = tp(vo0), pe1 = tp(ve1), po1 = tp(vo1);        \
    OUT_G0.x = pe0.lo; OUT_G0.y = pe0.hi; OUT_G0.z = po0.lo; OUT_G0.w = po0.hi; \
    OUT_G1.x = pe1.lo; OUT_G1.y = pe1.hi; OUT_G1.z = po1.lo; OUT_G1.w = po1.hi; \
    FENCE();                                                               \
  } while (0)

#define L5_MI(MI) do {                                                                        \
    f32x4 bb = ldf4(smem, SM_B5 + (MI)*64 + q*16);                                            \
    f32x4 a0 = bb, a1 = bb;                                                                   \
    half8 A;                                                                                  \
    A = lda(smem, SM_W5 + ((MI)*4+0)*1024 + ln*16); a0 = mfma16(A, c5g0_0, a0); a1 = mfma16(A, c5g1_0, a1); \
    A = lda(smem, SM_W5 + ((MI)*4+1)*1024 + ln*16); a0 = mfma16(A, c5g0_1, a0); a1 = mfma16(A, c5g1_1, a1); \
    A = lda(smem, SM_W5 + ((MI)*4+2)*1024 + ln*16); a0 = mfma16(A, c5g0_2, a0); a1 = mfma16(A, c5g1_2, a1); \
    A = lda(smem, SM_W5 + ((MI)*4+3)*1024 + ln*16); a0 = mfma16(A, c5g0_3, a0); a1 = mfma16(A, c5g1_3, a1); \
    f32x4 wo = ldf4(smem, SM_WO + (MI)*64 + q*16);                                            \
    part0 += sig2(a0.x)*wo.x + sig2(a0.y)*wo.y + sig2(a0.z)*wo.z + sig2(a0.w)*wo.w;           \
    part1 += sig2(a1.x)*wo.x + sig2(a1.y)*wo.y + sig2(a1.z)*wo.z + sig2(a1.w)*wo.w;           \
    FENCE();                                                                                  \
  } while (0)

__global__ __launch_bounds__(512)
void gnn_k2(const int4v* __restrict__ zbuf, float* __restrict__ out)
{
  __shared__ __align__(16) char smem[K2_LDS];
  const int tid = threadIdx.x;
  const int wv = tid >> 6, ln = tid & 63;

  // ---- stage k2 image region [K2_BASE, K2_BASE + K2_LDS) linearly ----
#pragma unroll 1
  for (int r = 0; r < 10; ++r) {
    int cb = (r * 8 + wv) << 6;
    if (cb < K2_LDS / 16) {
      stage_chunk(g_img + K2_BASE + (size_t)cb * 16 + ln * 16,
                  smem + (size_t)cb * 16 + ln * 16);
    }
  }
  __syncthreads();

  const int q = ln >> 4, c = ln & 15;
  const float bo2 = *(const float*)(smem + SM_EXTRA);   // bo - Sum Wo

  const int NG = N_NODES / 32;                // 15625 exactly
  const int g0i = blockIdx.x * 8 + wv;
  const int gstep = gridDim.x << 3;
#pragma unroll 1
  for (int g = g0i; g < NG; g += gstep) {
    const int base = g * 32;

    // ---- reload z (sigma); lanes 32+ rows have zero W4 rows anyway ----
    int4v zv = {0, 0, 0, 0};
    if (ln < 32) zv = zbuf[(size_t)g * 32 + ln];

    int4v b4g0, b4g1;
    b4g0.x = zv.x; b4g0.y = zv.y; b4g0.z = 0; b4g0.w = 0;
    b4g1.x = zv.z; b4g1.y = zv.w; b4g1.z = 0; b4g1.w = 0;

    // ---- L4: 6 -> 128 -> L5 B-frags ----
    int4v c5g0_0, c5g0_1, c5g0_2, c5g0_3;
    int4v c5g1_0, c5g1_1, c5g1_2, c5g1_3;
    L4_PAIR(0, c5g0_0, c5g1_0);
    L4_PAIR(1, c5g0_1, c5g1_1);
    L4_PAIR(2, c5g0_2, c5g1_2);
    L4_PAIR(3, c5g0_3, c5g1_3);

    // ---- L5 + output: out = sigma(Sum wo'*s5 + bo') ----
    float part0 = 0.0f, part1 = 0.0f;
    L5_MI(0);  L5_MI(1);  L5_MI(2);  L5_MI(3);
    L5_MI(4);  L5_MI(5);  L5_MI(6);  L5_MI(7);
    L5_MI(8);  L5_MI(9);  L5_MI(10); L5_MI(11);
    L5_MI(12); L5_MI(13); L5_MI(14); L5_MI(15);

    part0 += __shfl_xor(part0, 16, 64); part0 += __shfl_xor(part0, 32, 64);
    part1 += __shfl_xor(part1, 16, 64); part1 += __shfl_xor(part1, 32, 64);
    if (q < 2) {
      int node = base + q * 16 + c;
      float v = ((q == 0) ? part0 : part1) + bo2;
      out[node] = sigmoid_f(v);
    }
  }
}

extern "C" void kernel_launch(void* const* d_in, const int* in_sizes, int n_in,
                              void* d_out, int out_size, void* d_ws, size_t ws_size,
                              hipStream_t stream) {
  (void)in_sizes; (void)n_in; (void)ws_size; (void)out_size;
  const float* ea  = (const float*)d_in[2];
  const float* W1  = (const float*)d_in[3];
  const float* b1  = (const float*)d_in[4];
  const float* We1 = (const float*)d_in[5];
  const float* be1 = (const float*)d_in[6];
  const float* We2 = (const float*)d_in[7];
  const float* be2 = (const float*)d_in[8];
  const float* Wd1 = (const float*)d_in[9];
  const float* bd1 = (const float*)d_in[10];
  const float* Wd2 = (const float*)d_in[11];
  const float* bd2 = (const float*)d_in[12];
  const float* Wo  = (const float*)d_in[13];
  const float* bo  = (const float*)d_in[14];

  gnn_prep<<<dim3(156), dim3(256), 0, stream>>>(
      W1, b1, We1, be1, We2, be2, Wd1, bd1, Wd2, bd2, Wo, bo);
  gnn_k1<<<dim3(512), dim3(512), 0, stream>>>(ea, (int4v*)d_ws);
  gnn_k2<<<dim3(512), dim3(512), 0, stream>>>((const int4v*)d_ws, (float*)d_out);
}